// Round 5
// baseline (315.354 us; speedup 1.0000x reference)
//
#include <hip/hip_runtime.h>
#include <math.h>

#define BS 2
#define NQ 21760
#define V_LEN 21760
#define EMBED 256
#define NH 8
#define NL 4
#define NP 4
#define HD 32
#define M_TOT (BS * NQ)          // 43520
#define MN (M_TOT * EMBED)       // 11141120 elements
#define VPAD 256                 // byte pad around vproj for edge reads

typedef _Float16 f16;
typedef _Float16 half8 __attribute__((ext_vector_type(8)));
typedef _Float16 half4v __attribute__((ext_vector_type(4)));
typedef float f32x4 __attribute__((ext_vector_type(4)));

// ---------------- cast value||query fp32 -> f16 (float4 granularity)
__global__ __launch_bounds__(256) void cast2(
    const float* __restrict__ value, const float* __restrict__ query,
    f16* __restrict__ vq16)
{
    const int n4 = MN / 4;
    int i = blockIdx.x * 256 + threadIdx.x;
    const float4* s;
    int j;
    if (i < n4) { s = (const float4*)value; j = i; }
    else        { s = (const float4*)query; j = i - n4; }
    float4 f = s[j];
    half4v h;
    h[0] = (f16)f.x; h[1] = (f16)f.y; h[2] = (f16)f.z; h[3] = (f16)f.w;
    ((half4v*)vq16)[i] = h;
}

// ---------------- prep: transpose+cast weights to f16 WT[n][k], concat bias.
__global__ __launch_bounds__(256) void prep(
    const float* __restrict__ W_v, const float* __restrict__ W_off,
    const float* __restrict__ W_attn, const float* __restrict__ W_out,
    const float* __restrict__ b_off, const float* __restrict__ b_attn,
    f16* __restrict__ WTv, f16* __restrict__ WToa, f16* __restrict__ WTu,
    float* __restrict__ bcat)
{
    const int nb = blockIdx.x;
    const int k = threadIdx.x;
    if (nb < 256) {
        WTv[nb * 256 + k] = (f16)W_v[k * 256 + nb];
    } else if (nb < 640) {
        int j = nb - 256;
        float w = (j < 256) ? W_off[k * 256 + j] : W_attn[k * 128 + (j - 256)];
        WToa[j * 256 + k] = (f16)w;
    } else if (nb < 896) {
        int j = nb - 640;
        WTu[j * 256 + k] = (f16)W_out[k * 256 + j];
    } else if (nb == 896) {
        bcat[k] = b_off[k];
        if (k < 128) bcat[256 + k] = b_attn[k];
    }
}

// ---------------- barrier-free 128x128 GEMM, K=256, all-register fragments.
// OUTMODE 0: fp32 row-major. OUTMODE 2: f16 head-major vproj [b][h][v][32].
template<int OUTMODE>
__device__ __forceinline__ void gemm_direct(
    const f16* __restrict__ A, const f16* __restrict__ WT,
    const float* __restrict__ bias, float* __restrict__ Cf,
    f16* __restrict__ Ch, int N, int bm, int bn)
{
    const int tid = threadIdx.x;
    const int lane = tid & 63, wv = tid >> 6;
    const int wr = wv >> 1, wc = wv & 1;
    const int quad = lane >> 4, l16 = lane & 15;

    const f16* Ap = A  + (size_t)(bm + wr * 64 + l16) * 256 + quad * 8;
    const f16* Bp = WT + (size_t)(bn + wc * 64 + l16) * 256 + quad * 8;

    f32x4 acc[4][4];
    #pragma unroll
    for (int i = 0; i < 4; i++)
        #pragma unroll
        for (int j = 0; j < 4; j++)
            acc[i][j] = (f32x4){0.f, 0.f, 0.f, 0.f};

    #pragma unroll
    for (int ks = 0; ks < 8; ks++) {
        half8 af[4], bf[4];
        #pragma unroll
        for (int mi = 0; mi < 4; mi++)
            af[mi] = *(const half8*)(Ap + mi * 16 * 256 + ks * 32);
        #pragma unroll
        for (int ni = 0; ni < 4; ni++)
            bf[ni] = *(const half8*)(Bp + ni * 16 * 256 + ks * 32);
        #pragma unroll
        for (int mi = 0; mi < 4; mi++)
            #pragma unroll
            for (int ni = 0; ni < 4; ni++)
                acc[mi][ni] = __builtin_amdgcn_mfma_f32_16x16x32_f16(
                    af[mi], bf[ni], acc[mi][ni], 0, 0, 0);
    }

    const int bb = (bm >= NQ) ? 1 : 0;  // batch of this row-tile (tiles don't straddle)
    #pragma unroll
    for (int mi = 0; mi < 4; mi++) {
        #pragma unroll
        for (int ni = 0; ni < 4; ni++) {
            const int col = bn + wc * 64 + ni * 16 + l16;
            const int row0 = bm + wr * 64 + mi * 16 + quad * 4;
            const float bc = bias[col];
            if constexpr (OUTMODE == 0) {
                #pragma unroll
                for (int r = 0; r < 4; r++)
                    Cf[(size_t)(row0 + r) * N + col] = acc[mi][ni][r] + bc;
            } else {
                const int v0 = row0 - bb * NQ;
                const size_t hb = (size_t)(bb * 8 + (col >> 5)) * V_LEN;
                const int c = col & 31;
                #pragma unroll
                for (int r = 0; r < 4; r++)
                    Ch[(hb + v0 + r) * 32 + c] = (f16)(acc[mi][ni][r] + bc);
            }
        }
    }
}

// blocks [0,680): vproj (head-major f16).  [680,1700): offaw fp32, N=384.
__global__ __launch_bounds__(256) void front_gemm(
    const f16* __restrict__ vq16, const f16* __restrict__ WTv,
    const f16* __restrict__ WToa, const float* __restrict__ b_v,
    const float* __restrict__ bcat, f16* __restrict__ vp,
    float* __restrict__ offaw)
{
    int bid = blockIdx.x;
    if (bid < 680) {
        int bnt = bid & 1, bmt = bid >> 1;
        gemm_direct<2>(vq16, WTv, b_v, nullptr, vp, 256, bmt * 128, bnt * 128);
    } else {
        int b2 = bid - 680;
        int bnt = b2 % 3, bmt = b2 / 3;
        gemm_direct<0>(vq16 + MN, WToa, bcat, offaw, nullptr, 384, bmt * 128, bnt * 128);
    }
}

__global__ __launch_bounds__(256) void out_gemm(
    const f16* __restrict__ samp, const f16* __restrict__ WTu,
    const float* __restrict__ b_out, float* __restrict__ out)
{
    int bnt = blockIdx.x & 1, bmt = blockIdx.x >> 1;
    gemm_direct<0>(samp, WTu, b_out, out, nullptr, 256, bmt * 128, bnt * 128);
}

// ---------------- Deformable sampling: 4 waves/block, one query per wave.
// vp: head-major f16 [b][h][v][32], pointer is into padded buffer (VPAD front).
__global__ __launch_bounds__(256) void deform_sample(
    const f16* __restrict__ vp, const float* __restrict__ offaw,
    const float* __restrict__ refp, f16* __restrict__ sampled)
{
    const int wv = threadIdx.x >> 6;
    const int lane = threadIdx.x & 63;
    const int q = blockIdx.x * 4 + wv;
    const int b = blockIdx.y;
    const int bq = b * NQ + q;

    __shared__ float s_off[4][256];
    __shared__ float s_aw[4][128];
    __shared__ __align__(8)  f16 s_w[4][128][4];
    __shared__ __align__(8)  int s_idx[4][128][2];

    const float* row = offaw + (size_t)bq * 384;
    #pragma unroll
    for (int i = 0; i < 4; i++) s_off[wv][lane + i * 64] = row[lane + i * 64];
    #pragma unroll
    for (int i = 0; i < 2; i++) s_aw[wv][lane + i * 64] = row[256 + lane + i * 64];
    __syncthreads();

    if (lane < 8) {
        float m = -1e30f;
        #pragma unroll
        for (int i = 0; i < 16; i++) m = fmaxf(m, s_aw[wv][lane * 16 + i]);
        float ssum = 0.f;
        #pragma unroll
        for (int i = 0; i < 16; i++) {
            float e = __expf(s_aw[wv][lane * 16 + i] - m);
            s_aw[wv][lane * 16 + i] = e;
            ssum += e;
        }
        float r = 1.0f / ssum;
        #pragma unroll
        for (int i = 0; i < 16; i++) s_aw[wv][lane * 16 + i] *= r;
    }
    __syncthreads();

    // precompute 128 samples; storage d = lp*8 + h, lane computes d = lane+64*sI
    #pragma unroll
    for (int sI = 0; sI < 2; sI++) {
        int d = lane + sI * 64;
        int h = d & 7, lp = d >> 3, l = lp >> 2, p = lp & 3;
        int Wl = 128 >> l;
        int st = (l == 0) ? 0 : (l == 1) ? 16384 : (l == 2) ? 20480 : 21504;
        float rx = refp[(size_t)bq * 8 + l * 2 + 0];
        float ry = refp[(size_t)bq * 8 + l * 2 + 1];
        float ox = s_off[wv][((h * NL + l) * NP + p) * 2 + 0];
        float oy = s_off[wv][((h * NL + l) * NP + p) * 2 + 1];
        float fW = (float)Wl;
        float x = (rx + ox / fW) * fW - 0.5f;
        float y = (ry + oy / fW) * fW - 0.5f;
        float xf = floorf(x), yf = floorf(y);
        int x0 = (int)xf, y0 = (int)yf;
        float wx1 = x - xf, wx0 = 1.f - wx1;
        float wy1 = y - yf, wy0 = 1.f - wy1;
        float aw = s_aw[wv][h * 16 + lp];
        bool vx0 = (x0 >= 0) && (x0 < Wl);
        bool vx1 = (x0 + 1 >= 0) && (x0 + 1 < Wl);
        bool vy0 = (y0 >= 0) && (y0 < Wl);
        bool vy1 = (y0 + 1 >= 0) && (y0 + 1 < Wl);
        int cy0 = min(max(y0, 0), Wl - 1), cy1 = min(max(y0 + 1, 0), Wl - 1);
        int xc  = min(max(x0, -1), Wl - 1);   // address base; OOB corners have w=0
        half4v w4;
        w4[0] = (f16)((vy0 && vx0) ? wy0 * wx0 * aw : 0.f);
        w4[1] = (f16)((vy0 && vx1) ? wy0 * wx1 * aw : 0.f);
        w4[2] = (f16)((vy1 && vx0) ? wy1 * wx0 * aw : 0.f);
        w4[3] = (f16)((vy1 && vx1) ? wy1 * wx1 * aw : 0.f);
        *(half4v*)&s_w[wv][d][0] = w4;
        int2 i2;
        i2.x = (st + cy0 * Wl + xc) << 6;   // byte offset of 128-B (x0||x1) row pair
        i2.y = (st + cy1 * Wl + xc) << 6;
        *(int2*)&s_idx[wv][d][0] = i2;
    }
    __syncthreads();

    // gather: 8 lanes per head; lane j covers 16 B of the 128-B corner pair
    const int h = lane >> 3, j = lane & 7;
    const int jo = j * 16;
    const char* vb = (const char*)vp + (size_t)(b * 8 + h) * (V_LEN * 64);
    float a[8] = {0.f, 0.f, 0.f, 0.f, 0.f, 0.f, 0.f, 0.f};
    #pragma unroll 4
    for (int lp = 0; lp < 16; lp++) {
        const int d = lp * 8 + h;
        const int2 i2 = *(const int2*)&s_idx[wv][d][0];
        const half4v w4 = *(const half4v*)&s_w[wv][d][0];
        half8 v0 = *(const half8*)(vb + (i2.x + jo));
        half8 v1 = *(const half8*)(vb + (i2.y + jo));
        float w0 = (float)(j < 4 ? w4[0] : w4[1]);
        float w1 = (float)(j < 4 ? w4[2] : w4[3]);
        #pragma unroll
        for (int c = 0; c < 8; c++)
            a[c] += w0 * (float)v0[c] + w1 * (float)v1[c];
    }
    #pragma unroll
    for (int c = 0; c < 8; c++) a[c] += __shfl_xor(a[c], 4, 64);

    if (j < 4) {
        half8 o;
        #pragma unroll
        for (int c = 0; c < 8; c++) o[c] = (f16)a[c];
        *(half8*)&sampled[(size_t)bq * 256 + h * 32 + j * 8] = o;
    }
}

extern "C" void kernel_launch(void* const* d_in, const int* in_sizes, int n_in,
                              void* d_out, int out_size, void* d_ws, size_t ws_size,
                              hipStream_t stream)
{
    const float* query  = (const float*)d_in[0];
    const float* refp   = (const float*)d_in[1];
    const float* value  = (const float*)d_in[2];
    const float* W_off  = (const float*)d_in[3];
    const float* b_off  = (const float*)d_in[4];
    const float* W_attn = (const float*)d_in[5];
    const float* b_attn = (const float*)d_in[6];
    const float* W_v    = (const float*)d_in[7];
    const float* b_v    = (const float*)d_in[8];
    const float* W_out  = (const float*)d_in[9];
    const float* b_out  = (const float*)d_in[10];
    float* out = (float*)d_out;

    char* ws = (char*)d_ws;
    f16*   WTv   = (f16*)ws;    ws += 256 * 256 * 2;
    f16*   WToa  = (f16*)ws;    ws += 384 * 256 * 2;
    f16*   WTu   = (f16*)ws;    ws += 256 * 256 * 2;
    float* bcat  = (float*)ws;  ws += 384 * 4 + 512;
    f16*   vq16  = (f16*)ws;    ws += (size_t)2 * MN * 2;        // value||query f16
    ws += VPAD;
    f16*   vp    = (f16*)ws;    ws += (size_t)MN * 2 + VPAD;     // head-major vproj (padded)
    float* offaw = (float*)ws;  ws += (size_t)M_TOT * 384 * 4;
    f16*   samp  = (f16*)ws;    ws += (size_t)MN * 2;

    cast2<<<2 * MN / 4 / 256, 256, 0, stream>>>(value, query, vq16);
    prep<<<897, 256, 0, stream>>>(W_v, W_off, W_attn, W_out, b_off, b_attn,
                                  WTv, WToa, WTu, bcat);
    front_gemm<<<1700, 256, 0, stream>>>(vq16, WTv, WToa, b_v, bcat, vp, offaw);
    deform_sample<<<dim3(NQ / 4, BS), 256, 0, stream>>>(vp, offaw, refp, samp);
    out_gemm<<<680, 256, 0, stream>>>(samp, WTu, b_out, out);
}